// Round 16
// baseline (367.468 us; speedup 1.0000x reference)
//
#include <hip/hip_runtime.h>
#include <hip/hip_bf16.h>
#include <stdint.h>

// TernaryLinear: out = scale * (x_bf16 @ wq_bf16^T), scale = mean|W|+1e-8
// M=8192, K=2048, N=8192. fp32 in/out.
//
// GEMM: R15 (R11 skeleton + 32x32x16 MFMA) with ONE change: the per-row LDS
// swizzle constant s_r = (r&7) ^ ((r>>3)&7)  [was r&7].
// Why: 32-row fragments read slot g=(h2+2kf) ^ s_r; with s_r=r&7 the lanes
// {l,l+8,l+16,l+24} share r&7 and g -> 4 lanes on one 16B slot = 4-way bank
// conflict (measured 2.5e7, +36us). New s_r makes rows at distance 8/16/24
// differ (via (r>>3)&7) while aligned 8-row runs stay distinct; every lane-
// window census now matches R11's proven 0-conflict pattern. s_{r+64}=s_r
// (64>>3=8==0 mod 8), so 2-gload staging is unchanged; write-source and read
// use the same involution (both-sides rule).
//   ph1: STAGE B(T+1)h0 | rd A01,B0 (12) | MFMA Q(mb01,nb0)
//   ph2: STAGE B(T+1)h1 | rd A23 (8)     | MFMA Q(mb23,nb0) | SBAR (buf.A dead)
//   ph3: STAGE A(T+2)h0 | rd B1 (4)      | MFMA Q(mb01,nb1)
//   ph4: STAGE A(T+2)h1 |                | MFMA Q(mb23,nb1) | vm(4) SBAR
// C/D layout: col=lane&31, row=(reg&3)+8*(reg>>2)+4*(lane>>5)  [verified R15,
// absmax 0.0156]. WAR/RAW ledger = R11's.

typedef __attribute__((ext_vector_type(8)))  short s16x8;
typedef __attribute__((ext_vector_type(16))) float f32x16;

#define K_DIM   2048
#define K2      4096        // row stride bytes (bf16)
#define N_DIM   8192
#define N4      4194304     // 8192*2048/4

// ---------------- scale reduction ----------------
__global__ void k_abs_part(const float4* __restrict__ w4, float* __restrict__ part) {
    int tid = blockIdx.x * 256 + threadIdx.x;
    float s = 0.f;
    for (int i = tid; i < N4; i += gridDim.x * 256) {
        float4 v = w4[i];
        s += fabsf(v.x) + fabsf(v.y) + fabsf(v.z) + fabsf(v.w);
    }
    for (int off = 32; off > 0; off >>= 1) s += __shfl_down(s, off, 64);
    __shared__ float tmp[4];
    int lane = threadIdx.x & 63, wid = threadIdx.x >> 6;
    if (lane == 0) tmp[wid] = s;
    __syncthreads();
    if (threadIdx.x == 0) part[blockIdx.x] = tmp[0] + tmp[1] + tmp[2] + tmp[3];
}

__global__ void k_abs_final(const float* __restrict__ part, float* __restrict__ scale) {
    float s = part[threadIdx.x] + part[threadIdx.x + 256] +
              part[threadIdx.x + 512] + part[threadIdx.x + 768];
    for (int off = 32; off > 0; off >>= 1) s += __shfl_down(s, off, 64);
    __shared__ float tmp[4];
    int lane = threadIdx.x & 63, wid = threadIdx.x >> 6;
    if (lane == 0) tmp[wid] = s;
    __syncthreads();
    if (threadIdx.x == 0) scale[0] = (tmp[0] + tmp[1] + tmp[2] + tmp[3]) / 16777216.0f + 1e-8f;
}

// ---------------- fused W-quant + X-convert ----------------
__device__ __forceinline__ uint32_t f2b(float f) {
    uint32_t u = __builtin_bit_cast(uint32_t, f);
    return (u + 0x7FFFu + ((u >> 16) & 1u)) >> 16;  // RNE
}

__global__ void k_prep(const float4* __restrict__ w4, const float4* __restrict__ x4,
                       const float* __restrict__ scale_p,
                       uint2* __restrict__ wq, uint2* __restrict__ xb) {
    int tid = (blockIdx.x & 2047) * 256 + threadIdx.x;
    if (blockIdx.x < 2048) {
        const float sc = *scale_p;
        for (int i = tid; i < N4; i += 2048 * 256) {
            float4 v = w4[i];
            float q0 = rintf(v.x / sc), q1 = rintf(v.y / sc);
            float q2 = rintf(v.z / sc), q3 = rintf(v.w / sc);
            uint32_t b0 = (q0 == 0.f) ? 0u : (q0 > 0.f ? 0x3F80u : 0xBF80u);
            uint32_t b1 = (q1 == 0.f) ? 0u : (q1 > 0.f ? 0x3F80u : 0xBF80u);
            uint32_t b2 = (q2 == 0.f) ? 0u : (q2 > 0.f ? 0x3F80u : 0xBF80u);
            uint32_t b3 = (q3 == 0.f) ? 0u : (q3 > 0.f ? 0x3F80u : 0xBF80u);
            uint2 o; o.x = b0 | (b1 << 16); o.y = b2 | (b3 << 16);
            wq[i] = o;
        }
    } else {
        for (int i = tid; i < N4; i += 2048 * 256) {
            float4 v = x4[i];
            uint2 o;
            o.x = f2b(v.x) | (f2b(v.y) << 16);
            o.y = f2b(v.z) | (f2b(v.w) << 16);
            xb[i] = o;
        }
    }
}

// ---------------- GEMM ----------------
__device__ __forceinline__ void mfma32(f32x16& c, s16x8 a, s16x8 b) {
    asm("v_mfma_f32_32x32x16_bf16 %0, %1, %2, %0" : "+v"(c) : "v"(a), "v"(b));
}
__device__ __forceinline__ void load_lds16(const void* g, void* l) {
    __builtin_amdgcn_global_load_lds(
        (const __attribute__((address_space(1))) uint32_t*)g,
        (__attribute__((address_space(3))) uint32_t*)l, 16, 0, 0);
}

#define SCHED0 __builtin_amdgcn_sched_barrier(0)
#define SBAR do { SCHED0; __builtin_amdgcn_s_barrier(); SCHED0; } while (0)
#define WAIT_VM(N) do { asm volatile("s_waitcnt vmcnt(" #N ")" ::: "memory"); SCHED0; } while (0)

// LDS byte map (128 KiB): buf0.A=0, buf0.B=32768, buf1.A=65536, buf1.B=98304
#define C0 0
#define C1 65536

// per-row swizzle constant: s_r = (r&7) ^ ((r>>3)&7); note s_{r+64} = s_r
#define SWZ(R) (((R) & 7) ^ (((R) >> 3) & 7))

__global__ __launch_bounds__(512, 2) void k_gemm(
    const unsigned short* __restrict__ Xb,
    const unsigned short* __restrict__ Wb,
    const float* __restrict__ scale_p,
    float* __restrict__ out)
{
    extern __shared__ uint8_t smem[];
    const int tid  = threadIdx.x;
    const int lane = tid & 63;
    const int wid  = tid >> 6;
    const int wr   = wid >> 2;          // 0..1
    const int wc   = wid & 3;           // 0..3

    // 4x8 supertiled XCD mapping (bijective; proven R11: FETCH 549->200MB)
    const int bid = blockIdx.x;
    const int xcd = bid & 7;
    const int l   = bid >> 3;
    const int tileRow = xcd * 4 + ((l >> 3) & 3);   // 0..31
    const int tileCol = (l >> 5) * 8 + (l & 7);     // 0..31

    const uint8_t* gA = (const uint8_t*)Xb + (size_t)tileRow * 256 * K2;
    const uint8_t* gB = (const uint8_t*)Wb + (size_t)tileCol * 256 * K2;

    // staging: physical LDS slot c of row r holds global col-slot c ^ SWZ(r).
    // Thread t writes phys slot (t&7) of rows t>>3 (and +64 via 2nd gload,
    // same SWZ) -> source must be global slot (t&7)^SWZ(srow).
    const int srow = tid >> 3, sslot = tid & 7;
    const size_t srcOff = (size_t)srow * K2 + (size_t)((sslot ^ SWZ(srow)) * 16);
    const uint8_t* gAs = gA + srcOff;
    const uint8_t* gBs = gB + srcOff;
    const int dstOff = tid * 16;

    // 32x32 frag reads: row = base + mb*32 + (lane&31); global slot g =
    // (lane>>5) + 2*kf; physical = g ^ SWZ(row).
    const int h2 = lane >> 5;            // 0..1 (k-group)
    const int rA0 = wr * 128 + (lane & 31);
    const int rB0 = wc * 64  + (lane & 31);

    s16x8 a[4][4], b[2][4];
    f32x16 acc[4][2];
    #pragma unroll
    for (int mb = 0; mb < 4; ++mb)
        #pragma unroll
        for (int nb = 0; nb < 2; ++nb)
            #pragma unroll
            for (int j = 0; j < 16; ++j) acc[mb][nb][j] = 0.f;

#define LD8(OFF) (*(const s16x8*)(smem + (OFF)))
#define STAGE(LBASE, GP, BOFF) do { \
    load_lds16((GP) + (BOFF),          smem + (LBASE) + dstOff); \
    load_lds16((GP) + (BOFF) + 262144, smem + (LBASE) + 8192 + dstOff); \
    SCHED0; } while (0)

// A-frag read: region base AB, m-blocks MB0..MB0+1, all kf
#define RD_A2(AB, MB0) do { _Pragma("unroll") for (int mb = (MB0); mb < (MB0)+2; ++mb) { \
    const int r_ = rA0 + mb * 32; const int s_ = SWZ(r_); \
    _Pragma("unroll") for (int kf = 0; kf < 4; ++kf) \
        a[mb][kf] = LD8((AB) + r_ * 128 + (((h2 + 2*kf) ^ s_) * 16)); } } while (0)
// B-frag read: n-block NB, all kf (B region at AB+32768)
#define RD_B1N(AB, NB) do { \
    const int r_ = rB0 + (NB) * 32; const int s_ = SWZ(r_); \
    _Pragma("unroll") for (int kf = 0; kf < 4; ++kf) \
        b[(NB)][kf] = LD8((AB) + 32768 + r_ * 128 + (((h2 + 2*kf) ^ s_) * 16)); } while (0)

// Quadrant: m-blocks MB0..MB0+1 x n-block NB, K=64 (kf 0..3) = 8 MFMA
#define MFMA_Q(MB0, NB) do { \
    __builtin_amdgcn_s_setprio(1); \
    _Pragma("unroll") for (int kf = 0; kf < 4; ++kf) \
        _Pragma("unroll") for (int mb = (MB0); mb < (MB0)+2; ++mb) \
            mfma32(acc[mb][(NB)], a[mb][kf], b[(NB)][kf]); \
    __builtin_amdgcn_s_setprio(0); \
    SCHED0; } while (0)

    // prologue (R11-identical): stage tiles 0 (C0) and 1 (C1) fully; force
    // tile 0, leave tile 1's 8 loads in flight.
    STAGE(C0,         gAs, 0);   STAGE(C0 + 16384, gAs, 524288);
    STAGE(C0 + 32768, gBs, 0);   STAGE(C0 + 49152, gBs, 524288);
    STAGE(C1,         gAs, 128); STAGE(C1 + 16384, gAs, 524288 + 128);
    STAGE(C1 + 32768, gBs, 128); STAGE(C1 + 49152, gBs, 524288 + 128);
    WAIT_VM(8);
    SBAR;

    #pragma unroll 1
    for (int i = 0; i < 15; ++i) {
        const int kb1 = (2 * i + 1) * 128;   // T+1
        const int kb2 = kb1 + 128;           // T+2
        const int kb3 = kb1 + 256;           // T+3
        // ---- even tile T on C0 ----
        // ph1
        STAGE(C1 + 32768, gBs, kb1);
        RD_A2(C0, 0); RD_B1N(C0, 0);
        MFMA_Q(0, 0);
        // ph2
        STAGE(C1 + 49152, gBs, 524288 + kb1);
        RD_A2(C0, 2);
        MFMA_Q(2, 0);
        SBAR;                                   // buf0.A dead
        // ph3
        STAGE(C0, gAs, kb2);
        RD_B1N(C0, 1);
        MFMA_Q(0, 1);
        // ph4
        STAGE(C0 + 16384, gAs, 524288 + kb2);
        MFMA_Q(2, 1);
        WAIT_VM(4); SBAR;                       // T+1 landed; buf0.B dead
        // ---- odd tile T+1 on C1 ----
        // ph5
        STAGE(C0 + 32768, gBs, kb2);
        RD_A2(C1, 0); RD_B1N(C1, 0);
        MFMA_Q(0, 0);
        // ph6
        STAGE(C0 + 49152, gBs, 524288 + kb2);
        RD_A2(C1, 2);
        MFMA_Q(2, 0);
        SBAR;                                   // buf1.A dead
        // ph7
        STAGE(C1, gAs, kb3);
        RD_B1N(C1, 1);
        MFMA_Q(0, 1);
        // ph8
        STAGE(C1 + 16384, gAs, 524288 + kb3);
        MFMA_Q(2, 1);
        WAIT_VM(4); SBAR;                       // T+2 landed; buf1.B dead
    }

    // peeled i=15: tiles 30 (C0), 31 (C1); stage only B_31; then drain
    {
        const int kb1 = 31 * 128;
        STAGE(C1 + 32768, gBs, kb1);
        RD_A2(C0, 0); RD_B1N(C0, 0);
        MFMA_Q(0, 0);
        STAGE(C1 + 49152, gBs, 524288 + kb1);
        RD_A2(C0, 2);
        MFMA_Q(2, 0);
        SBAR;
        RD_B1N(C0, 1);
        MFMA_Q(0, 1);
        MFMA_Q(2, 1);
        WAIT_VM(0); SBAR;                       // all of tile 31 landed
        RD_A2(C1, 0); RD_B1N(C1, 0);
        MFMA_Q(0, 0);
        RD_A2(C1, 2);
        MFMA_Q(2, 0);
        RD_B1N(C1, 1);
        MFMA_Q(0, 1);
        MFMA_Q(2, 1);
    }

    // epilogue: 32x32 C/D layout: col = lane&31, row = (j&3)+8*(j>>2)+4*(lane>>5)
    const float sc = *scale_p;
    const int orow0 = tileRow * 256 + wr * 128 + 4 * h2;
    const int ocol0 = tileCol * 256 + wc * 64 + (lane & 31);
    #pragma unroll
    for (int mb = 0; mb < 4; ++mb)
        #pragma unroll
        for (int nb = 0; nb < 2; ++nb)
            #pragma unroll
            for (int j = 0; j < 16; ++j) {
                const int row = orow0 + mb * 32 + (j & 3) + 8 * (j >> 2);
                out[(size_t)row * N_DIM + (ocol0 + nb * 32)] = acc[mb][nb][j] * sc;
            }

#undef LD8
#undef STAGE
#undef RD_A2
#undef RD_B1N
#undef MFMA_Q
}

// ---------------- launch ----------------
extern "C" void kernel_launch(void* const* d_in, const int* in_sizes, int n_in,
                              void* d_out, int out_size, void* d_ws, size_t ws_size,
                              hipStream_t stream) {
    const float* x = (const float*)d_in[0];
    const float* w = (const float*)d_in[1];
    float* out = (float*)d_out;
    uint8_t* ws = (uint8_t*)d_ws;

    float* part  = (float*)ws;                       // 1024 floats
    float* scale = (float*)(ws + 4096);              // 1 float
    unsigned short* Xb = (unsigned short*)(ws + 8192);
    unsigned short* Wb = (unsigned short*)(ws + 8192 + 33554432ull);

    (void)hipFuncSetAttribute((const void*)k_gemm,
                              hipFuncAttributeMaxDynamicSharedMemorySize, 131072);

    hipLaunchKernelGGL(k_abs_part, dim3(1024), dim3(256), 0, stream, (const float4*)w, part);
    hipLaunchKernelGGL(k_abs_final, dim3(1), dim3(256), 0, stream, part, scale);
    hipLaunchKernelGGL(k_prep, dim3(4096), dim3(256), 0, stream,
                       (const float4*)w, (const float4*)x, scale, (uint2*)Wb, (uint2*)Xb);
    hipLaunchKernelGGL(k_gemm, dim3(1024), dim3(512), 131072, stream, Xb, Wb, scale, out);
}

// Round 17
// 276.429 us; speedup vs baseline: 1.3293x; 1.3293x over previous
//
#include <hip/hip_runtime.h>
#include <hip/hip_bf16.h>
#include <stdint.h>

// TernaryLinear: out = scale * (x_bf16 @ wq_bf16^T), scale = mean|W|+1e-8
// M=8192, K=2048, N=8192. fp32 in/out.
//
// GEMM: R11 byte-identical EXCEPT all __builtin_amdgcn_sched_barrier(0) are
// removed (m141 lesson: order-pinning defeats the compiler's near-optimal
// counted-lgkm scheduling; 874->510 TF in the guide's measurement).
// Ordering safety without SCHED0: inline-asm vm-waits carry "memory" clobber
// (orders all compiler-visible LDS/global ops both ways); s_barrier and
// global_load_lds builtins have unmodeled side effects (memory ops cannot
// cross); MFMAs are data-dependent on ds_read results. The R11 WAR/RAW ledger
// is unchanged:
//   ph1: STAGE B(T+1)h0 | rd a03,b01 (12) | MFMA Q00
//   ph2: STAGE B(T+1)h1 | rd a47 (8)      | MFMA Q40 | BAR (buf.A dead)
//   ph3: STAGE A(T+2)h0 | rd b23 (4)      | MFMA Q02
//   ph4: STAGE A(T+2)h1 |                 | MFMA Q42 | vm(4) BAR (T+1 landed)
// 4x8 supertiled XCD mapping (proven R11: FETCH 549->200MB).

typedef __attribute__((ext_vector_type(8))) short   s16x8;
typedef __attribute__((ext_vector_type(4))) float   f32x4;

#define K_DIM   2048
#define K2      4096        // row stride bytes (bf16)
#define N_DIM   8192
#define N4      4194304     // 8192*2048/4

// ---------------- scale reduction ----------------
__global__ void k_abs_part(const float4* __restrict__ w4, float* __restrict__ part) {
    int tid = blockIdx.x * 256 + threadIdx.x;
    float s = 0.f;
    for (int i = tid; i < N4; i += gridDim.x * 256) {
        float4 v = w4[i];
        s += fabsf(v.x) + fabsf(v.y) + fabsf(v.z) + fabsf(v.w);
    }
    for (int off = 32; off > 0; off >>= 1) s += __shfl_down(s, off, 64);
    __shared__ float tmp[4];
    int lane = threadIdx.x & 63, wid = threadIdx.x >> 6;
    if (lane == 0) tmp[wid] = s;
    __syncthreads();
    if (threadIdx.x == 0) part[blockIdx.x] = tmp[0] + tmp[1] + tmp[2] + tmp[3];
}

__global__ void k_abs_final(const float* __restrict__ part, float* __restrict__ scale) {
    float s = part[threadIdx.x] + part[threadIdx.x + 256] +
              part[threadIdx.x + 512] + part[threadIdx.x + 768];
    for (int off = 32; off > 0; off >>= 1) s += __shfl_down(s, off, 64);
    __shared__ float tmp[4];
    int lane = threadIdx.x & 63, wid = threadIdx.x >> 6;
    if (lane == 0) tmp[wid] = s;
    __syncthreads();
    if (threadIdx.x == 0) scale[0] = (tmp[0] + tmp[1] + tmp[2] + tmp[3]) / 16777216.0f + 1e-8f;
}

// ---------------- fused W-quant + X-convert ----------------
__device__ __forceinline__ uint32_t f2b(float f) {
    uint32_t u = __builtin_bit_cast(uint32_t, f);
    return (u + 0x7FFFu + ((u >> 16) & 1u)) >> 16;  // RNE
}

__global__ void k_prep(const float4* __restrict__ w4, const float4* __restrict__ x4,
                       const float* __restrict__ scale_p,
                       uint2* __restrict__ wq, uint2* __restrict__ xb) {
    int tid = (blockIdx.x & 2047) * 256 + threadIdx.x;
    if (blockIdx.x < 2048) {
        const float sc = *scale_p;
        for (int i = tid; i < N4; i += 2048 * 256) {
            float4 v = w4[i];
            float q0 = rintf(v.x / sc), q1 = rintf(v.y / sc);
            float q2 = rintf(v.z / sc), q3 = rintf(v.w / sc);
            uint32_t b0 = (q0 == 0.f) ? 0u : (q0 > 0.f ? 0x3F80u : 0xBF80u);
            uint32_t b1 = (q1 == 0.f) ? 0u : (q1 > 0.f ? 0x3F80u : 0xBF80u);
            uint32_t b2 = (q2 == 0.f) ? 0u : (q2 > 0.f ? 0x3F80u : 0xBF80u);
            uint32_t b3 = (q3 == 0.f) ? 0u : (q3 > 0.f ? 0x3F80u : 0xBF80u);
            uint2 o; o.x = b0 | (b1 << 16); o.y = b2 | (b3 << 16);
            wq[i] = o;
        }
    } else {
        for (int i = tid; i < N4; i += 2048 * 256) {
            float4 v = x4[i];
            uint2 o;
            o.x = f2b(v.x) | (f2b(v.y) << 16);
            o.y = f2b(v.z) | (f2b(v.w) << 16);
            xb[i] = o;
        }
    }
}

// ---------------- GEMM ----------------
__device__ __forceinline__ void mfma16(f32x4& c, s16x8 a, s16x8 b) {
    asm("v_mfma_f32_16x16x32_bf16 %0, %1, %2, %0" : "+v"(c) : "v"(a), "v"(b));
}
__device__ __forceinline__ void load_lds16(const void* g, void* l) {
    __builtin_amdgcn_global_load_lds(
        (const __attribute__((address_space(1))) uint32_t*)g,
        (__attribute__((address_space(3))) uint32_t*)l, 16, 0, 0);
}

// Bare primitives: NO sched_barrier(0) anywhere (m141: pinning defeats the
// compiler scheduler). "memory" clobber + side-effecting builtins preserve
// the required memory-op ordering.
#define SBAR __builtin_amdgcn_s_barrier()
#define WAIT_VM(N) asm volatile("s_waitcnt vmcnt(" #N ")" ::: "memory")

// LDS byte map (128 KiB): buf0.A=0, buf0.B=32768, buf1.A=65536, buf1.B=98304
#define C0 0
#define C1 65536

__global__ __launch_bounds__(512, 2) void k_gemm(
    const unsigned short* __restrict__ Xb,
    const unsigned short* __restrict__ Wb,
    const float* __restrict__ scale_p,
    float* __restrict__ out)
{
    extern __shared__ uint8_t smem[];
    const int tid  = threadIdx.x;
    const int lane = tid & 63;
    const int wid  = tid >> 6;
    const int wr   = wid >> 2;          // 0..1
    const int wc   = wid & 3;           // 0..3

    // 4x8 supertiled XCD mapping (bijective; proven R11: FETCH 549->200MB)
    const int bid = blockIdx.x;
    const int xcd = bid & 7;
    const int l   = bid >> 3;
    const int tileRow = xcd * 4 + ((l >> 3) & 3);   // 0..31
    const int tileCol = (l >> 5) * 8 + (l & 7);     // 0..31

    const uint8_t* gA = (const uint8_t*)Xb + (size_t)tileRow * 256 * K2;
    const uint8_t* gB = (const uint8_t*)Wb + (size_t)tileCol * 256 * K2;

    // staging: thread t covers row srow and srow+64 of a 128-row x 64-K half-region.
    // physical LDS slot c of row r holds global col-slot (c ^ (r&7))  (XOR swizzle).
    const int srow = tid >> 3, sslot = tid & 7;
    const size_t srcOff = (size_t)srow * K2 + (size_t)((sslot ^ (srow & 7)) * 16);
    const uint8_t* gAs = gA + srcOff;
    const uint8_t* gBs = gB + srcOff;
    const int dstOff = tid * 16;

    // LDS read bases (byte offsets); frag m adds m*2048 (16 rows * 128B)
    const int rA = wr * 128 + (lane & 15);
    const int rB = wc * 64  + (lane & 15);
    const int h  = lane >> 4;
    const int pA0 = rA * 128 + (((h    ) ^ (rA & 7)) * 16);
    const int pA1 = rA * 128 + (((4 + h) ^ (rA & 7)) * 16);
    const int pB0 = rB * 128 + (((h    ) ^ (rB & 7)) * 16);
    const int pB1 = rB * 128 + (((4 + h) ^ (rB & 7)) * 16);

    s16x8 a[8][2], b[4][2];
    f32x4 acc[8][4];
    #pragma unroll
    for (int m = 0; m < 8; ++m)
        #pragma unroll
        for (int n = 0; n < 4; ++n) acc[m][n] = (f32x4){0.f, 0.f, 0.f, 0.f};

#define LD8(OFF) (*(const s16x8*)(smem + (OFF)))
#define STAGE(LBASE, GP, BOFF) do { \
    load_lds16((GP) + (BOFF),          smem + (LBASE) + dstOff); \
    load_lds16((GP) + (BOFF) + 262144, smem + (LBASE) + 8192 + dstOff); } while (0)

#define RD_A03(AB) do { _Pragma("unroll") for (int m = 0; m < 4; ++m) { \
    a[m][0] = LD8((AB) + pA0 + m * 2048); a[m][1] = LD8((AB) + pA1 + m * 2048); } } while (0)
#define RD_A47(AB) do { _Pragma("unroll") for (int m = 4; m < 8; ++m) { \
    a[m][0] = LD8((AB) + pA0 + m * 2048); a[m][1] = LD8((AB) + pA1 + m * 2048); } } while (0)
#define RD_B01(AB) do { _Pragma("unroll") for (int n = 0; n < 2; ++n) { \
    b[n][0] = LD8((AB) + 32768 + pB0 + n * 2048); b[n][1] = LD8((AB) + 32768 + pB1 + n * 2048); } } while (0)
#define RD_B23(AB) do { _Pragma("unroll") for (int n = 2; n < 4; ++n) { \
    b[n][0] = LD8((AB) + 32768 + pB0 + n * 2048); b[n][1] = LD8((AB) + 32768 + pB1 + n * 2048); } } while (0)

#define MFMA_Q(MLO, NLO) do { \
    __builtin_amdgcn_s_setprio(1); \
    _Pragma("unroll") for (int kk = 0; kk < 2; ++kk) \
        _Pragma("unroll") for (int m = 0; m < 4; ++m) \
            _Pragma("unroll") for (int n = 0; n < 2; ++n) \
                mfma16(acc[(MLO) + m][(NLO) + n], a[(MLO) + m][kk], b[(NLO) + n][kk]); \
    __builtin_amdgcn_s_setprio(0); } while (0)

    // prologue: stage tiles 0 (C0) and 1 (C1) fully; force tile 0, leave tile
    // 1's 8 loads in flight.
    STAGE(C0,         gAs, 0);   STAGE(C0 + 16384, gAs, 524288);
    STAGE(C0 + 32768, gBs, 0);   STAGE(C0 + 49152, gBs, 524288);
    STAGE(C1,         gAs, 128); STAGE(C1 + 16384, gAs, 524288 + 128);
    STAGE(C1 + 32768, gBs, 128); STAGE(C1 + 49152, gBs, 524288 + 128);
    WAIT_VM(8);
    SBAR;

    #pragma unroll 1
    for (int i = 0; i < 15; ++i) {
        const int kb1 = (2 * i + 1) * 128;   // T+1
        const int kb2 = kb1 + 128;           // T+2
        const int kb3 = kb1 + 256;           // T+3
        // ---- even tile T on C0 ----
        // ph1
        STAGE(C1 + 32768, gBs, kb1);
        RD_A03(C0); RD_B01(C0);
        MFMA_Q(0, 0);
        // ph2
        STAGE(C1 + 49152, gBs, 524288 + kb1);
        RD_A47(C0);
        MFMA_Q(4, 0);
        SBAR;                                   // buf0.A dead
        // ph3
        STAGE(C0, gAs, kb2);
        RD_B23(C0);
        MFMA_Q(0, 2);
        // ph4
        STAGE(C0 + 16384, gAs, 524288 + kb2);
        MFMA_Q(4, 2);
        WAIT_VM(4); SBAR;                       // T+1 landed; buf0.B dead
        // ---- odd tile T+1 on C1 ----
        // ph5
        STAGE(C0 + 32768, gBs, kb2);
        RD_A03(C1); RD_B01(C1);
        MFMA_Q(0, 0);
        // ph6
        STAGE(C0 + 49152, gBs, 524288 + kb2);
        RD_A47(C1);
        MFMA_Q(4, 0);
        SBAR;                                   // buf1.A dead
        // ph7
        STAGE(C1, gAs, kb3);
        RD_B23(C1);
        MFMA_Q(0, 2);
        // ph8
        STAGE(C1 + 16384, gAs, 524288 + kb3);
        MFMA_Q(4, 2);
        WAIT_VM(4); SBAR;                       // T+2 landed; buf1.B dead
    }

    // peeled i=15: tiles 30 (C0), 31 (C1); stage only B_31; then drain
    {
        const int kb1 = 31 * 128;
        STAGE(C1 + 32768, gBs, kb1);
        RD_A03(C0); RD_B01(C0);
        MFMA_Q(0, 0);
        STAGE(C1 + 49152, gBs, 524288 + kb1);
        RD_A47(C0);
        MFMA_Q(4, 0);
        SBAR;
        RD_B23(C0);
        MFMA_Q(0, 2);
        MFMA_Q(4, 2);
        WAIT_VM(0); SBAR;                       // all of tile 31 landed
        RD_A03(C1); RD_B01(C1);
        MFMA_Q(0, 0);
        RD_A47(C1);
        MFMA_Q(4, 0);
        RD_B23(C1);
        MFMA_Q(0, 2);
        MFMA_Q(4, 2);
    }

    // epilogue: C[row][col], col=lane&15, row=(lane>>4)*4+j (verified mapping)
    const float sc = *scale_p;
    const int orow0 = tileRow * 256 + wr * 128 + ((lane >> 4) << 2);
    const int ocol0 = tileCol * 256 + wc * 64 + (lane & 15);
    #pragma unroll
    for (int m = 0; m < 8; ++m)
        #pragma unroll
        for (int n = 0; n < 4; ++n)
            #pragma unroll
            for (int j = 0; j < 4; ++j)
                out[(size_t)(orow0 + m * 16 + j) * N_DIM + (ocol0 + n * 16)] = acc[m][n][j] * sc;

#undef LD8
#undef STAGE
#undef RD_A03
#undef RD_A47
#undef RD_B01
#undef RD_B23
#undef MFMA_Q
}

// ---------------- launch ----------------
extern "C" void kernel_launch(void* const* d_in, const int* in_sizes, int n_in,
                              void* d_out, int out_size, void* d_ws, size_t ws_size,
                              hipStream_t stream) {
    const float* x = (const float*)d_in[0];
    const float* w = (const float*)d_in[1];
    float* out = (float*)d_out;
    uint8_t* ws = (uint8_t*)d_ws;

    float* part  = (float*)ws;                       // 1024 floats
    float* scale = (float*)(ws + 4096);              // 1 float
    unsigned short* Xb = (unsigned short*)(ws + 8192);
    unsigned short* Wb = (unsigned short*)(ws + 8192 + 33554432ull);

    (void)hipFuncSetAttribute((const void*)k_gemm,
                              hipFuncAttributeMaxDynamicSharedMemorySize, 131072);

    hipLaunchKernelGGL(k_abs_part, dim3(1024), dim3(256), 0, stream, (const float4*)w, part);
    hipLaunchKernelGGL(k_abs_final, dim3(1), dim3(256), 0, stream, part, scale);
    hipLaunchKernelGGL(k_prep, dim3(4096), dim3(256), 0, stream,
                       (const float4*)w, (const float4*)x, scale, (uint2*)Wb, (uint2*)Xb);
    hipLaunchKernelGGL(k_gemm, dim3(1024), dim3(512), 131072, stream, Xb, Wb, scale, out);
}